// Round 8
// baseline (1006.239 us; speedup 1.0000x reference)
//
#include <hip/hip_runtime.h>

typedef __bf16 bf16x8 __attribute__((ext_vector_type(8)));
typedef float f32x4 __attribute__((ext_vector_type(4)));
typedef int i32x4 __attribute__((ext_vector_type(4)));

#define MFMA(a, b, c) __builtin_amdgcn_mfma_f32_16x16x32_bf16((a), (b), (c), 0, 0, 0)
#define GLOAD_LDS(g, l) __builtin_amdgcn_global_load_lds( \
    (const __attribute__((address_space(1))) void*)(g),   \
    (__attribute__((address_space(3))) void*)(l), 16, 0, 0)

constexpr int HEADS = 8, SEQ = 4096, FIN = 512, HD = 64, FOUT = 512;
// 1/sqrt(64) * log2(e): fold softmax scale + exp->exp2 conversion into Q
constexpr float QSCALE = 0.18033688011112042f;

// DIAGNOSTIC ROUND: attn repeats its full computation REPS times inside one
// dispatch (bit-identical output; accumulators reinit per rep). Purpose: push
// attn's dispatch dur past the ~328us top-5 profiler cutoff (all larger
// dispatches are harness fills) so we finally observe its real counters after
// 5 structural probes whose subtraction-based models were all falsified.
constexpr int REPS = 2;

// Load 8 contiguous fp32, convert to a bf16x8 MFMA fragment (ptr must be 16B-aligned).
__device__ inline bf16x8 cvt8(const float* __restrict__ p) {
    f32x4 a = *(const f32x4*)p;
    f32x4 b = *(const f32x4*)(p + 4);
    bf16x8 r;
    r[0] = (__bf16)a[0]; r[1] = (__bf16)a[1]; r[2] = (__bf16)a[2]; r[3] = (__bf16)a[3];
    r[4] = (__bf16)b[0]; r[5] = (__bf16)b[1]; r[6] = (__bf16)b[2]; r[7] = (__bf16)b[3];
    return r;
}

// ---------------- Kernel 1: QKV projection (fp32 in -> bf16 ws) ----------------
__global__ __launch_bounds__(256) void qkv_kernel(
    const float* __restrict__ X, const float* __restrict__ Wq,
    const float* __restrict__ Wk, const float* __restrict__ Wv,
    __bf16* __restrict__ Q, __bf16* __restrict__ K, __bf16* __restrict__ Vt)
{
    const int h = blockIdx.y;
    const int tid = threadIdx.x;
    const int w = tid >> 6, lane = tid & 63;
    const int quad = lane >> 4, l16 = lane & 15;
    const int m = blockIdx.x * 64 + w * 16 + l16;

    const float* xrow = X + ((size_t)h * SEQ + m) * FIN + quad * 8;
    const float* wqh = Wq + (size_t)h * HD * FIN + quad * 8;
    const float* wkh = Wk + (size_t)h * HD * FIN + quad * 8;
    const float* wvh = Wv + (size_t)h * HD * FIN + quad * 8;

    const f32x4 vzero = {0.f, 0.f, 0.f, 0.f};
    f32x4 accQ[4], accK[4], accV[4];
#pragma unroll
    for (int t = 0; t < 4; ++t) { accQ[t] = vzero; accK[t] = vzero; accV[t] = vzero; }

    for (int f0 = 0; f0 < FIN; f0 += 32) {
        bf16x8 a = cvt8(xrow + f0);
#pragma unroll
        for (int t = 0; t < 4; ++t) {
            const int wrow = (t * 16 + l16) * FIN + f0;
            bf16x8 bq = cvt8(wqh + wrow);
            bf16x8 bk = cvt8(wkh + wrow);
            bf16x8 bv = cvt8(wvh + wrow);
            accQ[t] = MFMA(a, bq, accQ[t]);
            accK[t] = MFMA(a, bk, accK[t]);
            accV[t] = MFMA(a, bv, accV[t]);
        }
    }

    const int row0 = blockIdx.x * 64 + w * 16 + quad * 4;
#pragma unroll
    for (int t = 0; t < 4; ++t) {
        const int d = t * 16 + l16;
#pragma unroll
        for (int r = 0; r < 4; ++r) {
            const int n = row0 + r;
            Q[((size_t)h * SEQ + n) * HD + d] = (__bf16)(accQ[t][r] * QSCALE);
            K[((size_t)h * SEQ + n) * HD + d] = (__bf16)accK[t][r];
            Vt[((size_t)h * HD + d) * SEQ + n] = (__bf16)accV[t][r];
        }
    }
}

// ---------------- Kernel 2: masked flash attention, S^T layout ----------------
// EXACT r3-verified kernel (benched 889.5us, passed) wrapped in a REPS loop for
// profiler visibility. Sync skeleton frozen: barrier per 64-key tile, single
// dbuf pair, prefetch one tile ahead, mask ping-pong in regs, setprio around
// MFMA clusters, lsum in 4 accumulators.
// Pre-registered predictions for the attn dispatch (REPS=2):
//   dur 340-380us; MfmaUtil<10; VALUBusy<30; SQ_LDS_BANK_CONFLICT<1e6;
//   hbm ~3 TB/s  -> per-tile stage+vmcnt(0)+barrier convoy is the bottleneck.
// LDS: K dbuf [0,16K) | V dbuf [16K,32K) | PT 4x2048B
__global__ __launch_bounds__(256) void attn_kernel(
    const __bf16* __restrict__ Q, const __bf16* __restrict__ K,
    const __bf16* __restrict__ Vt, const int* __restrict__ mask,
    __bf16* __restrict__ Hcat)
{
    __shared__ __align__(16) unsigned char lds[32768 + 4 * 2048];

    const int bid = blockIdx.x;
    const int h = bid & 7;           // XCD-pinned head (round-robin dispatch heuristic)
    const int q0b = (bid >> 3) * 64;
    const int tid = threadIdx.x;
    const int w = tid >> 6, lane = tid & 63;
    const int quad = lane >> 4, l16 = lane & 15;
    const int q0 = q0b + w * 16;
    const int e7 = l16 & 7;          // XOR-swizzle key for this lane's rows

    __bf16* PT = (__bf16*)(lds + 32768) + w * 1024;  // 16 q-rows x 64, chunk-swizzled

    const __bf16* Qh = Q + (size_t)h * SEQ * HD;
    const __bf16* Kh = K + (size_t)h * SEQ * HD;
    const __bf16* Vh = Vt + (size_t)h * HD * SEQ;
    const int* mrow = mask + ((size_t)h * SEQ + q0 + l16) * SEQ + quad * 4;

    // issue K/V prefetch for tile at n0 into buffer b (XOR chunk swizzle:
    // LDS chunk s holds global chunk ((s&7)^(row&7)) of row s>>3)
    auto stage = [&](int n0, int b) {
        unsigned char* bK = lds + b * 8192;
        unsigned char* bV = lds + 16384 + b * 8192;
#pragma unroll
        for (int c = 0; c < 2; ++c) {
            const int s = c * 256 + w * 64 + lane;   // 0..511
            const int row = s >> 3;
            const int cq = (s & 7) ^ (row & 7);
            GLOAD_LDS(Kh + (size_t)(n0 + row) * HD + cq * 8, bK + (c * 256 + w * 64) * 16);
            GLOAD_LDS(Vh + (size_t)row * SEQ + n0 + cq * 8, bV + (c * 256 + w * 64) * 16);
        }
    };
    // mask for tile n0 -> 4 register i32x4 (lane's 16 key-columns)
    auto loadM = [&](int n0, i32x4* mv) {
#pragma unroll
        for (int t = 0; t < 4; ++t) mv[t] = *(const i32x4*)(mrow + n0 + t * 16);
    };

    // Q fragments (B operand) held in registers for the whole key loop
    bf16x8 qa0 = *(const bf16x8*)(Qh + (size_t)(q0 + l16) * HD + quad * 8);
    bf16x8 qa1 = *(const bf16x8*)(Qh + (size_t)(q0 + l16) * HD + 32 + quad * 8);

    const f32x4 vzero = {0.f, 0.f, 0.f, 0.f};
    f32x4 O[4];
    float ls0, ls1, ls2, ls3;

    auto tile = [&](int i, const i32x4* mc, i32x4* mn) {
        const int n0 = i * 64;
        const int cur = i & 1;
        if (i + 1 < SEQ / 64) {      // prefetch next tile (K/V -> LDS, mask -> regs)
            stage(n0 + 64, cur ^ 1);
            loadM(n0 + 64, mn);
        }
        const __bf16* cK = (const __bf16*)(lds + cur * 8192);
        const __bf16* cV = (const __bf16*)(lds + 16384 + cur * 8192);

        // ---- S^T = K . Q^T : lane owns q = q0+l16, keys = n0+t*16+quad*4+{0..3}
        f32x4 St[4];
        __builtin_amdgcn_s_setprio(1);
#pragma unroll
        for (int t = 0; t < 4; ++t) {
            const int kr = t * 16 + l16;
            bf16x8 kb0 = *(const bf16x8*)(cK + kr * 64 + ((quad ^ (kr & 7)) * 8));
            bf16x8 kb1 = *(const bf16x8*)(cK + kr * 64 + (((quad + 4) ^ (kr & 7)) * 8));
            St[t] = MFMA(kb0, qa0, vzero);   // A = K rows, B = Q rows -> S^T
            St[t] = MFMA(kb1, qa1, St[t]);
        }
        __builtin_amdgcn_s_setprio(0);

        // ---- p = mask ? exp2(s) : 0 ; pack 4 keys -> one ds_write_b64 ----
        // PT chunk-swizzle: key chunk c of row l16 lives at element ((c^e7)*8)
#pragma unroll
        for (int t = 0; t < 4; ++t) {
            union { unsigned long long u; __bf16 hh[4]; } pk;
            float psub0 = 0.f, psub1 = 0.f;
#pragma unroll
            for (int r = 0; r < 4; ++r) {
                float p = __builtin_amdgcn_exp2f(St[t][r]);
                p = mc[t][r] ? p : 0.f;
                if (r & 1) psub1 += p; else psub0 += p;
                pk.hh[r] = (__bf16)p;
            }
            // 4 independent accumulators: no 16-deep serial add chain
            if (t == 0) ls0 += psub0 + psub1;
            else if (t == 1) ls1 += psub0 + psub1;
            else if (t == 2) ls2 += psub0 + psub1;
            else ls3 += psub0 + psub1;
            const int c = t * 2 + (quad >> 1);   // 8-el chunk holding keys t*16+quad*4..+3
            *(unsigned long long*)(PT + l16 * 64 + ((c ^ e7) * 8) + (quad & 1) * 4) = pk.u;
        }

        // ---- O += P . V  (P in A layout from swizzled PT; V swizzled) ----
        bf16x8 pa0 = *(const bf16x8*)(PT + l16 * 64 + ((quad ^ e7) * 8));
        bf16x8 pa1 = *(const bf16x8*)(PT + l16 * 64 + (((quad + 4) ^ e7) * 8));
        __builtin_amdgcn_s_setprio(1);
#pragma unroll
        for (int t = 0; t < 4; ++t) {
            const int dr = t * 16 + l16;
            bf16x8 vb0 = *(const bf16x8*)(cV + dr * 64 + ((quad ^ (dr & 7)) * 8));
            bf16x8 vb1 = *(const bf16x8*)(cV + dr * 64 + (((quad + 4) ^ (dr & 7)) * 8));
            O[t] = MFMA(pa0, vb0, O[t]);
            O[t] = MFMA(pa1, vb1, O[t]);
        }
        __builtin_amdgcn_s_setprio(0);
        __syncthreads();  // drain prefetch + protect buffer reuse (single barrier)
    };

    for (int rep = 0; rep < REPS; ++rep) {
        // reinit accumulators: each rep recomputes the identical result
#pragma unroll
        for (int t = 0; t < 4; ++t) O[t] = vzero;
        ls0 = ls1 = ls2 = ls3 = 0.f;

        i32x4 mA[4], mB[4];
        stage(0, 0);                 // dbuf protocol restarts cleanly: final tile
        loadM(0, mA);                // of prev rep ended with __syncthreads()
        __syncthreads();

        for (int i = 0; i < SEQ / 64; i += 2) {   // ping-pong mask regs, no copies
            tile(i, mA, mB);
            tile(i + 1, mB, mA);
        }
    }

    // ---- l: reduce over the 4 quads holding q=l16, then transpose to C rows ----
    float lsum = (ls0 + ls1) + (ls2 + ls3);
    lsum += __shfl_xor(lsum, 16, 64);
    lsum += __shfl_xor(lsum, 32, 64);   // L[l16], uniform across quads
    float inv[4];
#pragma unroll
    for (int r = 0; r < 4; ++r) {
        float Lr = __shfl(lsum, quad * 4 + r, 64);
        inv[r] = Lr > 0.f ? 1.0f / Lr : 0.f;
    }

    // ---- epilogue: Hcat[n, h*64 + d] = O / l ----
#pragma unroll
    for (int r = 0; r < 4; ++r) {
        const int n = q0 + quad * 4 + r;
#pragma unroll
        for (int t = 0; t < 4; ++t)
            Hcat[(size_t)n * FOUT + h * HD + t * 16 + l16] = (__bf16)(O[t][r] * inv[r]);
    }
}

// ---------------- Kernel 3: output projection ----------------
__global__ __launch_bounds__(256) void out_kernel(
    const __bf16* __restrict__ Hcat, const float* __restrict__ Wo,
    float* __restrict__ out)
{
    const int tid = threadIdx.x;
    const int w = tid >> 6, lane = tid & 63;
    const int quad = lane >> 4, l16 = lane & 15;
    const int n0 = blockIdx.x * 64 + w * 16;
    const int o0 = blockIdx.y * 64;

    const f32x4 vzero = {0.f, 0.f, 0.f, 0.f};
    f32x4 acc[4];
#pragma unroll
    for (int t = 0; t < 4; ++t) acc[t] = vzero;

    for (int k0 = 0; k0 < FOUT; k0 += 32) {
        bf16x8 a = *(const bf16x8*)(Hcat + (size_t)(n0 + l16) * FOUT + k0 + quad * 8);
#pragma unroll
        for (int t = 0; t < 4; ++t) {
            bf16x8 b = cvt8(Wo + (size_t)(o0 + t * 16 + l16) * FOUT + k0 + quad * 8);
            acc[t] = MFMA(a, b, acc[t]);
        }
    }
#pragma unroll
    for (int t = 0; t < 4; ++t)
#pragma unroll
        for (int r = 0; r < 4; ++r)
            out[(size_t)(n0 + quad * 4 + r) * FOUT + o0 + t * 16 + l16] = acc[t][r];
}

extern "C" void kernel_launch(void* const* d_in, const int* in_sizes, int n_in,
                              void* d_out, int out_size, void* d_ws, size_t ws_size,
                              hipStream_t stream) {
    const float* X    = (const float*)d_in[0];
    const int*   mask = (const int*)d_in[1];
    const float* Wq   = (const float*)d_in[2];
    const float* Wk   = (const float*)d_in[3];
    const float* Wv   = (const float*)d_in[4];
    const float* Wo   = (const float*)d_in[5];
    float* out = (float*)d_out;

    __bf16* Q    = (__bf16*)d_ws;
    __bf16* K    = Q + (size_t)HEADS * SEQ * HD;
    __bf16* Vt   = K + (size_t)HEADS * SEQ * HD;
    __bf16* Hcat = Vt + (size_t)HEADS * HD * SEQ;

    qkv_kernel<<<dim3(SEQ / 64, HEADS), 256, 0, stream>>>(X, Wq, Wk, Wv, Q, K, Vt);
    attn_kernel<<<(SEQ / 64) * HEADS, 256, 0, stream>>>(Q, K, Vt, mask, Hcat);
    out_kernel<<<dim3(SEQ / 64, FOUT / 64), 256, 0, stream>>>(Hcat, Wo, out);
}

// Round 9
// 821.891 us; speedup vs baseline: 1.2243x; 1.2243x over previous
//
#include <hip/hip_runtime.h>

typedef __bf16 bf16x8 __attribute__((ext_vector_type(8)));
typedef float f32x4 __attribute__((ext_vector_type(4)));
typedef float f32x16 __attribute__((ext_vector_type(16)));
typedef int i32x4 __attribute__((ext_vector_type(4)));

#define MFMA16(a, b, c) __builtin_amdgcn_mfma_f32_16x16x32_bf16((a), (b), (c), 0, 0, 0)
#define MFMA32(a, b, c) __builtin_amdgcn_mfma_f32_32x32x16_bf16((a), (b), (c), 0, 0, 0)
#define GLOAD_LDS(g, l) __builtin_amdgcn_global_load_lds( \
    (const __attribute__((address_space(1))) void*)(g),   \
    (__attribute__((address_space(3))) void*)(l), 16, 0, 0)

constexpr int HEADS = 8, SEQ = 4096, FIN = 512, HD = 64, FOUT = 512;
// 1/sqrt(64) * log2(e): fold softmax scale + exp->exp2 conversion into Q
constexpr float QSCALE = 0.18033688011112042f;

// Load 8 contiguous fp32, convert to a bf16x8 MFMA fragment (ptr must be 16B-aligned).
__device__ inline bf16x8 cvt8(const float* __restrict__ p) {
    f32x4 a = *(const f32x4*)p;
    f32x4 b = *(const f32x4*)(p + 4);
    bf16x8 r;
    r[0] = (__bf16)a[0]; r[1] = (__bf16)a[1]; r[2] = (__bf16)a[2]; r[3] = (__bf16)a[3];
    r[4] = (__bf16)b[0]; r[5] = (__bf16)b[1]; r[6] = (__bf16)b[2]; r[7] = (__bf16)b[3];
    return r;
}

__device__ inline unsigned pack2(float a, float b) {
    union { unsigned u; __bf16 h[2]; } r;
    r.h[0] = (__bf16)a; r.h[1] = (__bf16)b;
    return r.u;
}

// ---------------- Kernel 0: weights fp32 -> bf16 (once; removes per-block cvt) --
__global__ __launch_bounds__(256) void wconv_kernel(
    const float* __restrict__ Wq, const float* __restrict__ Wk,
    const float* __restrict__ Wv, const float* __restrict__ Wo,
    __bf16* __restrict__ oq, __bf16* __restrict__ ok,
    __bf16* __restrict__ ov, __bf16* __restrict__ oo)
{
    const int which = blockIdx.y;
    const float* s = which == 0 ? Wq : which == 1 ? Wk : which == 2 ? Wv : Wo;
    __bf16* d = which == 0 ? oq : which == 1 ? ok : which == 2 ? ov : oo;
    const size_t i = ((size_t)blockIdx.x * 256 + threadIdx.x) * 8;  // 128x256x8 = 262144
    *(bf16x8*)(d + i) = cvt8(s + i);
}

// ---------------- Kernel 1: QKV projection (bf16 weights, fp32 X) --------------
__global__ __launch_bounds__(256) void qkv_kernel(
    const float* __restrict__ X, const __bf16* __restrict__ Wq,
    const __bf16* __restrict__ Wk, const __bf16* __restrict__ Wv,
    __bf16* __restrict__ Q, __bf16* __restrict__ K, __bf16* __restrict__ Vt)
{
    const int h = blockIdx.y;
    const int tid = threadIdx.x;
    const int w = tid >> 6, lane = tid & 63;
    const int quad = lane >> 4, l16 = lane & 15;
    const int m = blockIdx.x * 64 + w * 16 + l16;

    const float* xrow = X + ((size_t)h * SEQ + m) * FIN + quad * 8;
    const __bf16* wqh = Wq + (size_t)h * HD * FIN + quad * 8;
    const __bf16* wkh = Wk + (size_t)h * HD * FIN + quad * 8;
    const __bf16* wvh = Wv + (size_t)h * HD * FIN + quad * 8;

    const f32x4 vzero = {0.f, 0.f, 0.f, 0.f};
    f32x4 accQ[4], accK[4], accV[4];
#pragma unroll
    for (int t = 0; t < 4; ++t) { accQ[t] = vzero; accK[t] = vzero; accV[t] = vzero; }

    for (int f0 = 0; f0 < FIN; f0 += 32) {
        bf16x8 a = cvt8(xrow + f0);
#pragma unroll
        for (int t = 0; t < 4; ++t) {
            const int wrow = (t * 16 + l16) * FIN + f0;
            bf16x8 bq = *(const bf16x8*)(wqh + wrow);
            bf16x8 bk = *(const bf16x8*)(wkh + wrow);
            bf16x8 bv = *(const bf16x8*)(wvh + wrow);
            accQ[t] = MFMA16(a, bq, accQ[t]);
            accK[t] = MFMA16(a, bk, accK[t]);
            accV[t] = MFMA16(a, bv, accV[t]);
        }
    }

    const int row0 = blockIdx.x * 64 + w * 16 + quad * 4;
#pragma unroll
    for (int t = 0; t < 4; ++t) {
        const int d = t * 16 + l16;
#pragma unroll
        for (int r = 0; r < 4; ++r) {
            const int n = row0 + r;
            Q[((size_t)h * SEQ + n) * HD + d] = (__bf16)(accQ[t][r] * QSCALE);
            K[((size_t)h * SEQ + n) * HD + d] = (__bf16)accK[t][r];
            Vt[((size_t)h * HD + d) * SEQ + n] = (__bf16)accV[t][r];
        }
    }
}

// ---------------- Kernel 2: masked flash attention, 32x32 MFMA ----------------
// r8 diagnostic: attn = 119us; largest attackable term = LDS read BW (r3 kernel:
// 18 ds_read_b128/wave-tile ~ 46us) + PT LDS round-trip. This version keeps the
// r3-verified sync skeleton BYTE-IDENTICAL (same stage(), dbuf, ONE barrier per
// tile, mask ping-pong) and only changes intra-wave math to 32x32x16 MFMA
// (2x FLOP per operand byte):
//   * wave w owns (q-half = w>>1, key-half = w&1): QK^T 4 MFMAs reading 4 b128
//     of K; PV 4 MFMAs reading 4 b128 of V. 18 -> 8 b128/wave-tile.
//   * P stays IN-REGISTER: 32x32 C layout (col=lane&31=q, row=key) equals PV's
//     A layout up to a lane-half key swap, done with 4 shfl_xor(32)+selects
//     per k-step. PT LDS buffer eliminated entirely.
//   * O is key-partial per wave -> r7-style tail reduce via LDS aliased over
//     the dead dbuf (after final barrier; structure passed correctness in r7).
// LDS: loop K dbuf [0,16K) | V dbuf [16K,32K); tail Of[4][32][68]f32 + Lf[4][32].
__global__ __launch_bounds__(256) void attn_kernel(
    const __bf16* __restrict__ Q, const __bf16* __restrict__ K,
    const __bf16* __restrict__ Vt, const int* __restrict__ mask,
    __bf16* __restrict__ Hcat)
{
    __shared__ __align__(16) unsigned char lds[4 * 32 * 68 * 4 + 4 * 32 * 4]; // 35328B

    const int bid = blockIdx.x;
    const int h = bid & 7;           // XCD-pinned head (round-robin dispatch heuristic)
    const int q0b = (bid >> 3) * 64;
    const int tid = threadIdx.x;
    const int w = tid >> 6, lane = tid & 63;
    const int qh = w >> 1;           // wave's q-group (32 rows)
    const int kh = w & 1;            // wave's key-half within each 64-key tile
    const int l32 = lane & 31;       // q col (QK) / hd col (PV)
    const int hi = lane >> 5;        // lane half

    const __bf16* Qh = Q + (size_t)h * SEQ * HD;
    const __bf16* Kh = K + (size_t)h * SEQ * HD;
    const __bf16* Vh = Vt + (size_t)h * HD * SEQ;
    // lane reads mask[q0b+qh*32+l32][n0 + kh*32 + hi*4 + 8c + j]
    const int* mrow = mask + ((size_t)h * SEQ + q0b + qh * 32 + l32) * SEQ + kh * 32 + hi * 4;

    // stage: BYTE-IDENTICAL to r3-verified (XOR chunk swizzle, dbuf b)
    auto stage = [&](int n0, int b) {
        unsigned char* bK = lds + b * 8192;
        unsigned char* bV = lds + 16384 + b * 8192;
#pragma unroll
        for (int c = 0; c < 2; ++c) {
            const int s = c * 256 + w * 64 + lane;   // 0..511
            const int row = s >> 3;
            const int cq = (s & 7) ^ (row & 7);
            GLOAD_LDS(Kh + (size_t)(n0 + row) * HD + cq * 8, bK + (c * 256 + w * 64) * 16);
            GLOAD_LDS(Vh + (size_t)row * SEQ + n0 + cq * 8, bV + (c * 256 + w * 64) * 16);
        }
    };
    auto loadM = [&](int n0, i32x4* mv) {
#pragma unroll
        for (int c = 0; c < 4; ++c) mv[c] = *(const i32x4*)(mrow + n0 + c * 8);
    };

    // Q B-frags: col=q=l32 (fixed per lane), k = hd = s*16 + hi*8 + j
    bf16x8 qb[4];
#pragma unroll
    for (int s = 0; s < 4; ++s)
        qb[s] = *(const bf16x8*)(Qh + (size_t)(q0b + qh * 32 + l32) * HD + s * 16 + hi * 8);

    f32x16 O0 = {}, O1 = {};         // O[q-group][hd 0..31 / 32..63], key-partial
    float ls0 = 0.f, ls1 = 0.f, ls2 = 0.f, ls3 = 0.f;

    i32x4 mA[4], mB[4];
    stage(0, 0);
    loadM(0, mA);
    __syncthreads();

    const int krow = kh * 32 + l32;  // wave's K row in the 64-key tile
    const int ksw = krow & 7;

    auto tile = [&](int i, const i32x4* mc, i32x4* mn) {
        const int n0 = i * 64;
        const int cur = i & 1;
        if (i + 1 < SEQ / 64) {      // prefetch next tile (K/V -> LDS, mask -> regs)
            stage(n0 + 64, cur ^ 1);
            loadM(n0 + 64, mn);
        }
        const __bf16* cK = (const __bf16*)(lds + cur * 8192);
        const __bf16* cV = (const __bf16*)(lds + 16384 + cur * 8192);

        // ---- S^T[key][q] = K.Q^T, 32 keys x 32 q, k=hd in 4 steps of 16 ----
        f32x16 St = {};
        __builtin_amdgcn_s_setprio(1);
#pragma unroll
        for (int s = 0; s < 4; ++s) {
            bf16x8 ka = *(const bf16x8*)(cK + krow * 64 + (((2 * s + hi) ^ ksw) * 8));
            St = MFMA32(ka, qb[s], St);
        }
        __builtin_amdgcn_s_setprio(0);

        // ---- p = mask ? exp2(s) : 0. reg c*4+j <-> key kh*32 + 8c + j + 4hi ----
        float p[16];
#pragma unroll
        for (int c = 0; c < 4; ++c) {
            float a0 = 0.f, a1 = 0.f;
#pragma unroll
            for (int j = 0; j < 4; ++j) {
                float e = __builtin_amdgcn_exp2f(St[c * 4 + j]);
                e = mc[c][j] ? e : 0.f;
                if (j & 1) a1 += e; else a0 += e;
                p[c * 4 + j] = e;
            }
            if (c == 0) ls0 += a0 + a1;
            else if (c == 1) ls1 += a0 + a1;
            else if (c == 2) ls2 += a0 + a1;
            else ls3 += a0 + a1;
        }

        // ---- build PV A-frags in-register (lane-half key swap via shfl_xor 32)
        bf16x8 pa[2];
#pragma unroll
        for (int sp = 0; sp < 2; ++sp) {
            unsigned u0 = pack2(p[sp * 8 + 0], p[sp * 8 + 1]);
            unsigned u1 = pack2(p[sp * 8 + 2], p[sp * 8 + 3]);
            unsigned u2 = pack2(p[sp * 8 + 4], p[sp * 8 + 5]);
            unsigned u3 = pack2(p[sp * 8 + 6], p[sp * 8 + 7]);
            unsigned s0 = (unsigned)__shfl_xor((int)u0, 32, 64);
            unsigned s1 = (unsigned)__shfl_xor((int)u1, 32, 64);
            unsigned s2 = (unsigned)__shfl_xor((int)u2, 32, 64);
            unsigned s3 = (unsigned)__shfl_xor((int)u3, 32, 64);
            union { unsigned u[4]; bf16x8 v; } A;
            A.u[0] = hi ? s2 : u0;   // keys (0,1)L/(8,9)H   (+16sp+kh*32)
            A.u[1] = hi ? s3 : u1;   // keys (2,3)L/(10,11)H
            A.u[2] = hi ? u2 : s0;   // keys (4,5)L/(12,13)H
            A.u[3] = hi ? u3 : s1;   // keys (6,7)L/(14,15)H
            pa[sp] = A.v;
        }

        // ---- O += P.V over wave's 32 keys; B col = hd = G*32+l32 ----
        __builtin_amdgcn_s_setprio(1);
#pragma unroll
        for (int sp = 0; sp < 2; ++sp) {
            const int g = kh * 4 + 2 * sp + hi;              // key chunk
            bf16x8 vb0 = *(const bf16x8*)(cV + l32 * 64 + ((g ^ (l32 & 7)) * 8));
            bf16x8 vb1 = *(const bf16x8*)(cV + (32 + l32) * 64 + ((g ^ ((32 + l32) & 7)) * 8));
            O0 = MFMA32(pa[sp], vb0, O0);
            O1 = MFMA32(pa[sp], vb1, O1);
        }
        __builtin_amdgcn_s_setprio(0);
        __syncthreads();  // drain prefetch + protect buffer reuse (single barrier)
    };

    for (int i = 0; i < SEQ / 64; i += 2) {   // ping-pong mask regs, no copies
        tile(i, mA, mB);
        tile(i + 1, mB, mA);
    }

    // ---- tail: combine key-half partials via LDS (aliased over dead dbuf) ----
    float* Of = (float*)lds;                  // [4][32][68] (pad 68: conflict-free)
    float* Lf = (float*)lds + 4 * 32 * 68;    // [4][32]
    float lsum = (ls0 + ls1) + (ls2 + ls3);
    lsum += __shfl_xor(lsum, 32, 64);         // + other lane-half's keys
    float* myO = Of + w * (32 * 68);
#pragma unroll
    for (int r = 0; r < 16; ++r) {
        const int qr = (r & 3) + 8 * (r >> 2) + 4 * hi;      // q row within group
        myO[qr * 68 + l32] = O0[r];
        myO[qr * 68 + 32 + l32] = O1[r];
    }
    if (lane < 32) Lf[w * 32 + lane] = lsum;
    __syncthreads();

    // thread: q = tid>>2 (0..63), hd0 = (tid&3)*16
    const int q = tid >> 2, hd0 = (tid & 3) * 16;
    const int qg = q >> 5, q32 = q & 31;
    const float l = Lf[qg * 64 + q32] + Lf[qg * 64 + 32 + q32];
    const float inv = l > 0.f ? 1.0f / l : 0.f;
    float acc[16];
#pragma unroll
    for (int v = 0; v < 4; ++v) {
        f32x4 a = *(const f32x4*)(Of + (2 * qg) * (32 * 68) + q32 * 68 + hd0 + v * 4);
        f32x4 b = *(const f32x4*)(Of + (2 * qg + 1) * (32 * 68) + q32 * 68 + hd0 + v * 4);
#pragma unroll
        for (int j = 0; j < 4; ++j) acc[v * 4 + j] = a[j] + b[j];
    }
    bf16x8 o0, o1;
#pragma unroll
    for (int j = 0; j < 8; ++j) {
        o0[j] = (__bf16)(acc[j] * inv);
        o1[j] = (__bf16)(acc[8 + j] * inv);
    }
    __bf16* dst = Hcat + (size_t)(q0b + q) * FOUT + h * HD + hd0;
    *(bf16x8*)dst = o0;
    *(bf16x8*)(dst + 8) = o1;
}

// ---------------- Kernel 3: output projection (bf16 Wo) ----------------
__global__ __launch_bounds__(256) void out_kernel(
    const __bf16* __restrict__ Hcat, const __bf16* __restrict__ Wo,
    float* __restrict__ out)
{
    const int tid = threadIdx.x;
    const int w = tid >> 6, lane = tid & 63;
    const int quad = lane >> 4, l16 = lane & 15;
    const int n0 = blockIdx.x * 64 + w * 16;
    const int o0 = blockIdx.y * 64;

    const f32x4 vzero = {0.f, 0.f, 0.f, 0.f};
    f32x4 acc[4];
#pragma unroll
    for (int t = 0; t < 4; ++t) acc[t] = vzero;

    for (int k0 = 0; k0 < FOUT; k0 += 32) {
        bf16x8 a = *(const bf16x8*)(Hcat + (size_t)(n0 + l16) * FOUT + k0 + quad * 8);
#pragma unroll
        for (int t = 0; t < 4; ++t) {
            bf16x8 b = *(const bf16x8*)(Wo + (size_t)(o0 + t * 16 + l16) * FOUT + k0 + quad * 8);
            acc[t] = MFMA16(a, b, acc[t]);
        }
    }
#pragma unroll
    for (int t = 0; t < 4; ++t)
#pragma unroll
        for (int r = 0; r < 4; ++r)
            out[(size_t)(n0 + quad * 4 + r) * FOUT + o0 + t * 16 + l16] = acc[t][r];
}

extern "C" void kernel_launch(void* const* d_in, const int* in_sizes, int n_in,
                              void* d_out, int out_size, void* d_ws, size_t ws_size,
                              hipStream_t stream) {
    const float* X    = (const float*)d_in[0];
    const int*   mask = (const int*)d_in[1];
    const float* Wq   = (const float*)d_in[2];
    const float* Wk   = (const float*)d_in[3];
    const float* Wv   = (const float*)d_in[4];
    const float* Wo   = (const float*)d_in[5];
    float* out = (float*)d_out;

    __bf16* Q    = (__bf16*)d_ws;
    __bf16* K    = Q + (size_t)HEADS * SEQ * HD;
    __bf16* Vt   = K + (size_t)HEADS * SEQ * HD;
    __bf16* Hcat = Vt + (size_t)HEADS * HD * SEQ;
    __bf16* Wqb  = Hcat + (size_t)SEQ * FOUT;
    __bf16* Wkb  = Wqb + (size_t)HEADS * HD * FIN;
    __bf16* Wvb  = Wkb + (size_t)HEADS * HD * FIN;
    __bf16* Wob  = Wvb + (size_t)HEADS * HD * FIN;

    wconv_kernel<<<dim3(128, 4), 256, 0, stream>>>(Wq, Wk, Wv, Wo, Wqb, Wkb, Wvb, Wob);
    qkv_kernel<<<dim3(SEQ / 64, HEADS), 256, 0, stream>>>(X, Wqb, Wkb, Wvb, Q, K, Vt);
    attn_kernel<<<(SEQ / 64) * HEADS, 256, 0, stream>>>(Q, K, Vt, mask, Hcat);
    out_kernel<<<dim3(SEQ / 64, FOUT / 64), 256, 0, stream>>>(Hcat, Wob, out);
}

// Round 11
// 794.258 us; speedup vs baseline: 1.2669x; 1.0348x over previous
//
#include <hip/hip_runtime.h>

typedef __bf16 bf16x8 __attribute__((ext_vector_type(8)));
typedef float f32x4 __attribute__((ext_vector_type(4)));
typedef float f32x16 __attribute__((ext_vector_type(16)));
typedef int i32x4 __attribute__((ext_vector_type(4)));

#define MFMA16(a, b, c) __builtin_amdgcn_mfma_f32_16x16x32_bf16((a), (b), (c), 0, 0, 0)
#define MFMA32(a, b, c) __builtin_amdgcn_mfma_f32_32x32x16_bf16((a), (b), (c), 0, 0, 0)
#define GLOAD_LDS(g, l) __builtin_amdgcn_global_load_lds( \
    (const __attribute__((address_space(1))) void*)(g),   \
    (__attribute__((address_space(3))) void*)(l), 16, 0, 0)

constexpr int HEADS = 8, SEQ = 4096, FIN = 512, HD = 64, FOUT = 512;
// 1/sqrt(64) * log2(e): fold softmax scale + exp->exp2 conversion into Q
constexpr float QSCALE = 0.18033688011112042f;

// Load 8 contiguous fp32, convert to a bf16x8 MFMA fragment (ptr must be 16B-aligned).
__device__ inline bf16x8 cvt8(const float* __restrict__ p) {
    f32x4 a = *(const f32x4*)p;
    f32x4 b = *(const f32x4*)(p + 4);
    bf16x8 r;
    r[0] = (__bf16)a[0]; r[1] = (__bf16)a[1]; r[2] = (__bf16)a[2]; r[3] = (__bf16)a[3];
    r[4] = (__bf16)b[0]; r[5] = (__bf16)b[1]; r[6] = (__bf16)b[2]; r[7] = (__bf16)b[3];
    return r;
}

__device__ inline unsigned pack2(float a, float b) {
    union { unsigned u; __bf16 h[2]; } r;
    r.h[0] = (__bf16)a; r.h[1] = (__bf16)b;
    return r.u;
}

// ---------------- Kernel 0: weights fp32 -> bf16 (once; removes per-block cvt) --
__global__ __launch_bounds__(256) void wconv_kernel(
    const float* __restrict__ Wq, const float* __restrict__ Wk,
    const float* __restrict__ Wv, const float* __restrict__ Wo,
    __bf16* __restrict__ oq, __bf16* __restrict__ ok,
    __bf16* __restrict__ ov, __bf16* __restrict__ oo)
{
    const int which = blockIdx.y;
    const float* s = which == 0 ? Wq : which == 1 ? Wk : which == 2 ? Wv : Wo;
    __bf16* d = which == 0 ? oq : which == 1 ? ok : which == 2 ? ov : oo;
    const size_t i = ((size_t)blockIdx.x * 256 + threadIdx.x) * 8;  // 128x256x8 = 262144
    *(bf16x8*)(d + i) = cvt8(s + i);
}

// ---------------- Kernel 1: QKV projection (bf16 weights, fp32 X) --------------
__global__ __launch_bounds__(256) void qkv_kernel(
    const float* __restrict__ X, const __bf16* __restrict__ Wq,
    const __bf16* __restrict__ Wk, const __bf16* __restrict__ Wv,
    __bf16* __restrict__ Q, __bf16* __restrict__ K, __bf16* __restrict__ Vt)
{
    const int h = blockIdx.y;
    const int tid = threadIdx.x;
    const int w = tid >> 6, lane = tid & 63;
    const int quad = lane >> 4, l16 = lane & 15;
    const int m = blockIdx.x * 64 + w * 16 + l16;

    const float* xrow = X + ((size_t)h * SEQ + m) * FIN + quad * 8;
    const __bf16* wqh = Wq + (size_t)h * HD * FIN + quad * 8;
    const __bf16* wkh = Wk + (size_t)h * HD * FIN + quad * 8;
    const __bf16* wvh = Wv + (size_t)h * HD * FIN + quad * 8;

    const f32x4 vzero = {0.f, 0.f, 0.f, 0.f};
    f32x4 accQ[4], accK[4], accV[4];
#pragma unroll
    for (int t = 0; t < 4; ++t) { accQ[t] = vzero; accK[t] = vzero; accV[t] = vzero; }

    for (int f0 = 0; f0 < FIN; f0 += 32) {
        bf16x8 a = cvt8(xrow + f0);
#pragma unroll
        for (int t = 0; t < 4; ++t) {
            const int wrow = (t * 16 + l16) * FIN + f0;
            bf16x8 bq = *(const bf16x8*)(wqh + wrow);
            bf16x8 bk = *(const bf16x8*)(wkh + wrow);
            bf16x8 bv = *(const bf16x8*)(wvh + wrow);
            accQ[t] = MFMA16(a, bq, accQ[t]);
            accK[t] = MFMA16(a, bk, accK[t]);
            accV[t] = MFMA16(a, bv, accV[t]);
        }
    }

    const int row0 = blockIdx.x * 64 + w * 16 + quad * 4;
#pragma unroll
    for (int t = 0; t < 4; ++t) {
        const int d = t * 16 + l16;
#pragma unroll
        for (int r = 0; r < 4; ++r) {
            const int n = row0 + r;
            Q[((size_t)h * SEQ + n) * HD + d] = (__bf16)(accQ[t][r] * QSCALE);
            K[((size_t)h * SEQ + n) * HD + d] = (__bf16)accK[t][r];
            Vt[((size_t)h * HD + d) * SEQ + n] = (__bf16)accV[t][r];
        }
    }
}

// ---------------- Kernel 2: masked flash attention, 32x32 MFMA ----------------
// r9 (PASSED, 821.9): 32x32 MFMA, in-register P, key-half waves, tail reduce.
// SINGLE delta (T4, m218): tile-end __syncthreads() -> counted vmcnt barrier.
// Round 10 was an infra failure (never measured); resubmitted with one
// robustness fix: sched_barrier(0) BETWEEN stage() and loadM() pins the issue
// order (8 staging DMAs oldest, 4 mask reg-loads newest) that makes
// "s_waitcnt vmcnt(4)" retire ALL staging DMAs before s_barrier while the
// lane-private mask loads stay in flight across it (race-free: reg-destined).
// The barrier stops convoying on ~1us HBM mask latency every tile; the mask
// wait moves to its softmax use point (compiler-inserted, overlaps QK^T MFMAs).
// LDS: loop K dbuf [0,16K) | V dbuf [16K,32K); tail Of[4][32][68]f32 + Lf[4][32].
__global__ __launch_bounds__(256) void attn_kernel(
    const __bf16* __restrict__ Q, const __bf16* __restrict__ K,
    const __bf16* __restrict__ Vt, const int* __restrict__ mask,
    __bf16* __restrict__ Hcat)
{
    __shared__ __align__(16) unsigned char lds[4 * 32 * 68 * 4 + 4 * 32 * 4]; // 35328B

    const int bid = blockIdx.x;
    const int h = bid & 7;           // XCD-pinned head (round-robin dispatch heuristic)
    const int q0b = (bid >> 3) * 64;
    const int tid = threadIdx.x;
    const int w = tid >> 6, lane = tid & 63;
    const int qh = w >> 1;           // wave's q-group (32 rows)
    const int kh = w & 1;            // wave's key-half within each 64-key tile
    const int l32 = lane & 31;       // q col (QK) / hd col (PV)
    const int hi = lane >> 5;        // lane half

    const __bf16* Qh = Q + (size_t)h * SEQ * HD;
    const __bf16* Kh = K + (size_t)h * SEQ * HD;
    const __bf16* Vh = Vt + (size_t)h * HD * SEQ;
    // lane reads mask[q0b+qh*32+l32][n0 + kh*32 + hi*4 + 8c + j]
    const int* mrow = mask + ((size_t)h * SEQ + q0b + qh * 32 + l32) * SEQ + kh * 32 + hi * 4;

    // stage: BYTE-IDENTICAL to r3/r9-verified (XOR chunk swizzle, dbuf b)
    auto stage = [&](int n0, int b) {
        unsigned char* bK = lds + b * 8192;
        unsigned char* bV = lds + 16384 + b * 8192;
#pragma unroll
        for (int c = 0; c < 2; ++c) {
            const int s = c * 256 + w * 64 + lane;   // 0..511
            const int row = s >> 3;
            const int cq = (s & 7) ^ (row & 7);
            GLOAD_LDS(Kh + (size_t)(n0 + row) * HD + cq * 8, bK + (c * 256 + w * 64) * 16);
            GLOAD_LDS(Vh + (size_t)row * SEQ + n0 + cq * 8, bV + (c * 256 + w * 64) * 16);
        }
    };
    auto loadM = [&](int n0, i32x4* mv) {
#pragma unroll
        for (int c = 0; c < 4; ++c) mv[c] = *(const i32x4*)(mrow + n0 + c * 8);
    };

    // Q B-frags: col=q=l32 (fixed per lane), k = hd = s*16 + hi*8 + j
    bf16x8 qb[4];
#pragma unroll
    for (int s = 0; s < 4; ++s)
        qb[s] = *(const bf16x8*)(Qh + (size_t)(q0b + qh * 32 + l32) * HD + s * 16 + hi * 8);

    f32x16 O0 = {}, O1 = {};         // O[q-group][hd 0..31 / 32..63], key-partial
    float ls0 = 0.f, ls1 = 0.f, ls2 = 0.f, ls3 = 0.f;

    i32x4 mA[4], mB[4];
    stage(0, 0);
    loadM(0, mA);
    __syncthreads();                 // prologue: full drain once (simple, safe)

    const int krow = kh * 32 + l32;  // wave's K row in the 64-key tile
    const int ksw = krow & 7;

    auto tile = [&](int i, const i32x4* mc, i32x4* mn) {
        const int n0 = i * 64;
        const int cur = i & 1;
        if (i + 1 < SEQ / 64) {      // prefetch next tile: stage FIRST, masks LAST
            stage(n0 + 64, cur ^ 1);
            __builtin_amdgcn_sched_barrier(0);  // PIN issue order: all 8 DMAs
            loadM(n0 + 64, mn);                 // precede the 4 mask loads, so
            __builtin_amdgcn_sched_barrier(0);  // vmcnt(4) covers every DMA
        }
        const __bf16* cK = (const __bf16*)(lds + cur * 8192);
        const __bf16* cV = (const __bf16*)(lds + 16384 + cur * 8192);

        // ---- S^T[key][q] = K.Q^T, 32 keys x 32 q, k=hd in 4 steps of 16 ----
        f32x16 St = {};
        __builtin_amdgcn_s_setprio(1);
#pragma unroll
        for (int s = 0; s < 4; ++s) {
            bf16x8 ka = *(const bf16x8*)(cK + krow * 64 + (((2 * s + hi) ^ ksw) * 8));
            St = MFMA32(ka, qb[s], St);
        }
        __builtin_amdgcn_s_setprio(0);

        // ---- p = mask ? exp2(s) : 0. reg c*4+j <-> key kh*32 + 8c + j + 4hi ----
        float p[16];
#pragma unroll
        for (int c = 0; c < 4; ++c) {
            float a0 = 0.f, a1 = 0.f;
#pragma unroll
            for (int j = 0; j < 4; ++j) {
                float e = __builtin_amdgcn_exp2f(St[c * 4 + j]);
                e = mc[c][j] ? e : 0.f;
                if (j & 1) a1 += e; else a0 += e;
                p[c * 4 + j] = e;
            }
            if (c == 0) ls0 += a0 + a1;
            else if (c == 1) ls1 += a0 + a1;
            else if (c == 2) ls2 += a0 + a1;
            else ls3 += a0 + a1;
        }

        // ---- build PV A-frags in-register (lane-half key swap via shfl_xor 32)
        bf16x8 pa[2];
#pragma unroll
        for (int sp = 0; sp < 2; ++sp) {
            unsigned u0 = pack2(p[sp * 8 + 0], p[sp * 8 + 1]);
            unsigned u1 = pack2(p[sp * 8 + 2], p[sp * 8 + 3]);
            unsigned u2 = pack2(p[sp * 8 + 4], p[sp * 8 + 5]);
            unsigned u3 = pack2(p[sp * 8 + 6], p[sp * 8 + 7]);
            unsigned s0 = (unsigned)__shfl_xor((int)u0, 32, 64);
            unsigned s1 = (unsigned)__shfl_xor((int)u1, 32, 64);
            unsigned s2 = (unsigned)__shfl_xor((int)u2, 32, 64);
            unsigned s3 = (unsigned)__shfl_xor((int)u3, 32, 64);
            union { unsigned u[4]; bf16x8 v; } A;
            A.u[0] = hi ? s2 : u0;   // keys (0,1)L/(8,9)H   (+16sp+kh*32)
            A.u[1] = hi ? s3 : u1;   // keys (2,3)L/(10,11)H
            A.u[2] = hi ? u2 : s0;   // keys (4,5)L/(12,13)H
            A.u[3] = hi ? u3 : s1;   // keys (6,7)L/(14,15)H
            pa[sp] = A.v;
        }

        // ---- O += P.V over wave's 32 keys; B col = hd = G*32+l32 ----
        __builtin_amdgcn_s_setprio(1);
#pragma unroll
        for (int sp = 0; sp < 2; ++sp) {
            const int g = kh * 4 + 2 * sp + hi;              // key chunk
            bf16x8 vb0 = *(const bf16x8*)(cV + l32 * 64 + ((g ^ (l32 & 7)) * 8));
            bf16x8 vb1 = *(const bf16x8*)(cV + (32 + l32) * 64 + ((g ^ ((32 + l32) & 7)) * 8));
            O0 = MFMA32(pa[sp], vb0, O0);
            O1 = MFMA32(pa[sp], vb1, O1);
        }
        __builtin_amdgcn_s_setprio(0);

        // ---- T4 counted-vmcnt barrier: retire the 8 staging DMAs (oldest),
        // leave the 4 mask reg-loads (newest, lane-private) in flight ----
        asm volatile("s_waitcnt vmcnt(4)" ::: "memory");
        __builtin_amdgcn_s_barrier();
        __builtin_amdgcn_sched_barrier(0);
    };

    for (int i = 0; i < SEQ / 64; i += 2) {   // ping-pong mask regs, no copies
        tile(i, mA, mB);
        tile(i + 1, mB, mA);
    }

    // ---- tail: combine key-half partials via LDS (aliased over dead dbuf) ----
    // All DMAs retired here: final tile issues none, and its vmcnt(4) passes
    // with 0 outstanding; all waves crossed the final barrier.
    float* Of = (float*)lds;                  // [4][32][68] (pad 68: conflict-free)
    float* Lf = (float*)lds + 4 * 32 * 68;    // [4][32]
    float lsum = (ls0 + ls1) + (ls2 + ls3);
    lsum += __shfl_xor(lsum, 32, 64);         // + other lane-half's keys
    float* myO = Of + w * (32 * 68);
#pragma unroll
    for (int r = 0; r < 16; ++r) {
        const int qr = (r & 3) + 8 * (r >> 2) + 4 * hi;      // q row within group
        myO[qr * 68 + l32] = O0[r];
        myO[qr * 68 + 32 + l32] = O1[r];
    }
    if (lane < 32) Lf[w * 32 + lane] = lsum;
    __syncthreads();

    // thread: q = tid>>2 (0..63), hd0 = (tid&3)*16
    const int q = tid >> 2, hd0 = (tid & 3) * 16;
    const int qg = q >> 5, q32 = q & 31;
    const float l = Lf[qg * 64 + q32] + Lf[qg * 64 + 32 + q32];
    const float inv = l > 0.f ? 1.0f / l : 0.f;
    float acc[16];
#pragma unroll
    for (int v = 0; v < 4; ++v) {
        f32x4 a = *(const f32x4*)(Of + (2 * qg) * (32 * 68) + q32 * 68 + hd0 + v * 4);
        f32x4 b = *(const f32x4*)(Of + (2 * qg + 1) * (32 * 68) + q32 * 68 + hd0 + v * 4);
#pragma unroll
        for (int j = 0; j < 4; ++j) acc[v * 4 + j] = a[j] + b[j];
    }
    bf16x8 o0, o1;
#pragma unroll
    for (int j = 0; j < 8; ++j) {
        o0[j] = (__bf16)(acc[j] * inv);
        o1[j] = (__bf16)(acc[8 + j] * inv);
    }
    __bf16* dst = Hcat + (size_t)(q0b + q) * FOUT + h * HD + hd0;
    *(bf16x8*)dst = o0;
    *(bf16x8*)(dst + 8) = o1;
}

// ---------------- Kernel 3: output projection (bf16 Wo) ----------------
__global__ __launch_bounds__(256) void out_kernel(
    const __bf16* __restrict__ Hcat, const __bf16* __restrict__ Wo,
    float* __restrict__ out)
{
    const int tid = threadIdx.x;
    const int w = tid >> 6, lane = tid & 63;
    const int quad = lane >> 4, l16 = lane & 15;
    const int n0 = blockIdx.x * 64 + w * 16;
    const int o0 = blockIdx.y * 64;

    const f32x4 vzero = {0.f, 0.f, 0.f, 0.f};
    f32x4 acc[4];
#pragma unroll
    for (int t = 0; t < 4; ++t) acc[t] = vzero;

    for (int k0 = 0; k0 < FOUT; k0 += 32) {
        bf16x8 a = *(const bf16x8*)(Hcat + (size_t)(n0 + l16) * FOUT + k0 + quad * 8);
#pragma unroll
        for (int t = 0; t < 4; ++t) {
            bf16x8 b = *(const bf16x8*)(Wo + (size_t)(o0 + t * 16 + l16) * FOUT + k0 + quad * 8);
            acc[t] = MFMA16(a, b, acc[t]);
        }
    }
#pragma unroll
    for (int t = 0; t < 4; ++t)
#pragma unroll
        for (int r = 0; r < 4; ++r)
            out[(size_t)(n0 + quad * 4 + r) * FOUT + o0 + t * 16 + l16] = acc[t][r];
}

extern "C" void kernel_launch(void* const* d_in, const int* in_sizes, int n_in,
                              void* d_out, int out_size, void* d_ws, size_t ws_size,
                              hipStream_t stream) {
    const float* X    = (const float*)d_in[0];
    const int*   mask = (const int*)d_in[1];
    const float* Wq   = (const float*)d_in[2];
    const float* Wk   = (const float*)d_in[3];
    const float* Wv   = (const float*)d_in[4];
    const float* Wo   = (const float*)d_in[5];
    float* out = (float*)d_out;

    __bf16* Q    = (__bf16*)d_ws;
    __bf16* K    = Q + (size_t)HEADS * SEQ * HD;
    __bf16* Vt   = K + (size_t)HEADS * SEQ * HD;
    __bf16* Hcat = Vt + (size_t)HEADS * HD * SEQ;
    __bf16* Wqb  = Hcat + (size_t)SEQ * FOUT;
    __bf16* Wkb  = Wqb + (size_t)HEADS * HD * FIN;
    __bf16* Wvb  = Wkb + (size_t)HEADS * HD * FIN;
    __bf16* Wob  = Wvb + (size_t)HEADS * HD * FIN;

    wconv_kernel<<<dim3(128, 4), 256, 0, stream>>>(Wq, Wk, Wv, Wo, Wqb, Wkb, Wvb, Wob);
    qkv_kernel<<<dim3(SEQ / 64, HEADS), 256, 0, stream>>>(X, Wqb, Wkb, Wvb, Q, K, Vt);
    attn_kernel<<<(SEQ / 64) * HEADS, 256, 0, stream>>>(Q, K, Vt, mask, Hcat);
    out_kernel<<<dim3(SEQ / 64, FOUT / 64), 256, 0, stream>>>(Hcat, Wob, out);
}